// Round 15
// baseline (155.810 us; speedup 1.0000x reference)
//
#include <hip/hip_runtime.h>
#include <float.h>
#include <math.h>

#define NB 16
#define NN 577
#define NC 384
#define NH 6
#define ND 64
#define RPD2 2209
#define MTOT 9232
#define MPAD 9344
#define SCALE_ 0.125f
#define NEGBIG -3.0e38f
#define BSTRIDE 580
#define NKPAD 640

typedef __attribute__((ext_vector_type(8))) short bf16x8;
typedef __attribute__((ext_vector_type(4))) float f32x4;
typedef unsigned short u16;

#define MFMA16(a, b, c) __builtin_amdgcn_mfma_f32_16x16x32_bf16(a, b, c, 0, 0, 0)

// workspace offsets in u16 units
#define SQA 3932160ull                    // 96*640*64
#define OFF_QH 0ull
#define OFF_QL SQA
#define OFF_KH (2ull * SQA)
#define OFF_KL (3ull * SQA)
#define OFF_VTH (4ull * SQA)
#define OFF_VTL (5ull * SQA)
#define OFF_XH (6ull * SQA)               // aliased as Oh after qkv
#define OFF_XL (6ull * SQA + 3588096ull)  // aliased as Ol
#define OFF_WQH (6ull * SQA + 2ull * 3588096ull)
#define OFF_WQL (OFF_WQH + 442368ull)
#define OFF_WPH (OFF_WQL + 442368ull)
#define OFF_WPL (OFF_WPH + 147456ull)
#define OFF_BT  (OFF_WPL + 147456ull)
#define OFF_PM  (OFF_BT + 2007960ull)     // u32 region, 8B-aligned

static __device__ __forceinline__ u16 f2bf(float f) {
  unsigned u = __float_as_uint(f);
  u += 0x7fff + ((u >> 16) & 1);
  return (u16)(u >> 16);
}
static __device__ __forceinline__ float bf2f(u16 h) {
  return __uint_as_float((unsigned)h << 16);
}
static __device__ __forceinline__ void split2(float v, u16& hi, u16& lo) {
  hi = f2bf(v);
  lo = f2bf(v - bf2f(hi));
}
static __device__ __forceinline__ void gload16(const void* g, void* l) {
  __builtin_amdgcn_global_load_lds(
      (const __attribute__((address_space(1))) void*)g,
      (__attribute__((address_space(3))) void*)l, 16, 0, 0);
}
#define SB0() __builtin_amdgcn_sched_barrier(0)

// ---------------------------------------------------------------------------
// prep: split fp32 inputs into bf16 hi/lo (4080 blocks).
// ---------------------------------------------------------------------------
__global__ __launch_bounds__(256) void prep_k(
    const float* __restrict__ x, const float* __restrict__ wq,
    const float* __restrict__ wp, u16* __restrict__ ws)
{
  const int q = blockIdx.x * 256 + threadIdx.x;
  float4 v = {0.f, 0.f, 0.f, 0.f};
  u16 *dh, *dl;
  if (q < 897024) {
    if (q < 886272) v = ((const float4*)x)[q];
    dh = ws + OFF_XH + 4ull * q;
    dl = ws + OFF_XL + 4ull * q;
  } else if (q < 1007616) {
    int t = q - 897024;
    v = ((const float4*)wq)[t];
    dh = ws + OFF_WQH + 4ull * t;
    dl = ws + OFF_WQL + 4ull * t;
  } else {
    int t = q - 1007616;
    v = ((const float4*)wp)[t];
    dh = ws + OFF_WPH + 4ull * t;
    dl = ws + OFF_WPL + 4ull * t;
  }
  ushort4 hh, ll;
  split2(v.x, hh.x, ll.x);
  split2(v.y, hh.y, ll.y);
  split2(v.z, hh.z, ll.z);
  split2(v.w, hh.w, ll.w);
  *(ushort4*)dh = hh;
  *(ushort4*)dl = ll;
}

// ---------------------------------------------------------------------------
// QKV GEMM v9 (fused tails): triple-buffered LDS, single barrier per step,
// ledger-verified counted waits — NO wait ever touches a load issued in the
// same or previous step (S staged 2 ahead, B 1 ahead):
//   a: vmcnt(8)  completes S(k)   [enter: S(k),B(k),S(k+1) = 12]
//   barrier
//   c: issue B(k+1), S(k+2)       [16 outstanding]
//   d: vmcnt(12) completes B(k)   [leaves S(k+1),B(k+1),S(k+2) = 12]
//   e: COMPUTE(k)
// ---------------------------------------------------------------------------
__global__ __launch_bounds__(256, 3) void qkv_mfma_k(
    const u16* __restrict__ Xh, const u16* __restrict__ Xl,
    const u16* __restrict__ Wh, const u16* __restrict__ Wl,
    const float* __restrict__ bias, const int* __restrict__ mask,
    const float* __restrict__ rel_pos, const int* __restrict__ rel_idx,
    const int* __restrict__ patch, u16* __restrict__ ws)
{
  __shared__ u16 LB[24576];                // 48KB: A hi 3 bufs, A lo 3 bufs

  const int bid = blockIdx.x;
  const int tid = threadIdx.x;

  if (bid >= 1314) {
    if (bid < 3622) {                      // ---- pack mask -> bitmask ----
      unsigned* pm = (unsigned*)(ws + OFF_PM);
      const int pbid = bid - 1314;
      const int wid = (pbid * 256 + tid) >> 6;
      const int lane = tid & 63;
      if (wid >= MTOT) return;
      const int* mr = mask + (size_t)wid * NN;
#pragma unroll
      for (int c = 0; c < 10; ++c) {
        int k = c * 64 + lane;
        int v = (k < NN) ? mr[k] : 0;
        unsigned long long bal = __ballot(v != 0);
        if (lane == 0) pm[wid * 20 + 2 * c] = (unsigned)bal;
        if (lane == 1) pm[wid * 20 + 2 * c + 1] = (unsigned)(bal >> 32);
      }
    } else {                               // ---- bias table ----
      const int f = bid - 3622;            // 0..3461
      const int q = f % NN, h = f / NN;
      const int pa = *patch;
      u16* row = ws + OFF_BT + ((size_t)h * NN + q) * BSTRIDE;
      for (int kk = tid; kk < BSTRIDE; kk += 256) {
        float v = 0.f;
        if (pa && q >= 1 && kk >= 1 && kk < NN)
          v = rel_pos[h * RPD2 + rel_idx[(q - 1) * 576 + (kk - 1)]];
        row[kk] = f2bf(v);
      }
    }
    return;
  }

#define pASH(bf) (LB + (bf) * 4096)
#define pASL(bf) (LB + 12288 + (bf) * 4096)

  const int w = tid >> 6, l = tid & 63, lq = l & 15, lg = l >> 4;
  const int wm = (w >> 1) * 64, wn = (w & 1) * 32;

  // XCD-chunked bijective decode (1314 = 8*164 + 2), rb-fastest in chunk.
  const int o = bid;
  const int xcd = o & 7, rank = o >> 3;
  const int wg = (xcd < 2) ? (xcd * 165 + rank)
                           : (330 + (xcd - 2) * 164 + rank);
  const int mb = (wg / 18) * 128;
  const int rbi = wg % 18;
  const int rb = rbi * 64;
  const int r0 = rb + wn;
  const int soff = (l >> 2) * 384 + (l & 3) * 8;

#define STAGE_A(k0_, bf_)                                                    \
  {                                                                          \
    _Pragma("unroll")                                                        \
    for (int j = 0; j < 2; ++j) {                                            \
      const int tr = 32 * w + 16 * j;                                        \
      const size_t ga = (size_t)(mb + tr) * 384 + (k0_) + soff;              \
      gload16(&Xh[ga], pASH(bf_) + tr * 32);                                 \
      gload16(&Xl[ga], pASL(bf_) + tr * 32);                                 \
    }                                                                        \
  }

  const size_t brow = (size_t)(r0 + lq) * 384 + 8 * lg;
#define BLOAD(k0_, BH_, BL_)                                                 \
  {                                                                          \
    _Pragma("unroll")                                                        \
    for (int nt = 0; nt < 2; ++nt) {                                         \
      BH_[nt] = *(const bf16x8*)&Wh[brow + (size_t)(16 * nt) * 384 + (k0_)]; \
      BL_[nt] = *(const bf16x8*)&Wl[brow + (size_t)(16 * nt) * 384 + (k0_)]; \
    }                                                                        \
  }

#define COMPUTE(bf_, BH_, BL_)                                               \
  {                                                                          \
    _Pragma("unroll")                                                        \
    for (int mt = 0; mt < 4; ++mt) {                                         \
      bf16x8 ah = *(const bf16x8*)(pASH(bf_) + (wm + 16 * mt + lq) * 32 + 8 * lg); \
      bf16x8 al = *(const bf16x8*)(pASL(bf_) + (wm + 16 * mt + lq) * 32 + 8 * lg); \
      _Pragma("unroll")                                                      \
      for (int nt = 0; nt < 2; ++nt) {                                       \
        acc[mt][nt] = MFMA16(ah, BH_[nt], acc[mt][nt]);                      \
        acc[mt][nt] = MFMA16(ah, BL_[nt], acc[mt][nt]);                      \
        acc[mt][nt] = MFMA16(al, BH_[nt], acc[mt][nt]);                      \
      }                                                                      \
    }                                                                        \
  }

  bf16x8 bh2[2][2], bl2[2][2];
  // prologue (issue order matters for the ledger): S0, B0, S1
  STAGE_A(0, 0);
  BLOAD(0, bh2[0], bl2[0]);
  STAGE_A(32, 1);

  f32x4 acc[4][2];
#pragma unroll
  for (int nt = 0; nt < 2; ++nt) {
    float bv = bias[r0 + 16 * nt + lq];
#pragma unroll
    for (int mt = 0; mt < 4; ++mt) acc[mt][nt] = (f32x4){bv, bv, bv, bv};
  }

#pragma unroll
  for (int k = 0; k < 12; ++k) {
    // a: complete S(k) without touching anything newer
    if (k < 11) { asm volatile("s_waitcnt vmcnt(8)" ::: "memory"); }
    else        { asm volatile("s_waitcnt vmcnt(4)" ::: "memory"); }
    SB0();
    __builtin_amdgcn_s_barrier();          // S(k) visible; buf (k+2)%3 free
    SB0();
    // c: next-step loads (stay in flight across this step's waits)
    if (k < 11) BLOAD(32 * (k + 1), bh2[(k + 1) & 1], bl2[(k + 1) & 1]);
    if (k < 10) STAGE_A(32 * (k + 2), (k + 2) % 3);
    SB0();
    // d: complete B(k) exactly
    if (k < 10)      { asm volatile("s_waitcnt vmcnt(12)" ::: "memory"); }
    else if (k == 10){ asm volatile("s_waitcnt vmcnt(8)"  ::: "memory"); }
    else             { asm volatile("s_waitcnt vmcnt(0)"  ::: "memory"); }
    SB0();
    COMPUTE(k % 3, bh2[k & 1], bl2[k & 1]);
  }

#undef COMPUTE
#undef BLOAD
#undef STAGE_A

  const int comp = rbi / 6;                // block-uniform: 0=Q 1=K 2=V
  const int h = rbi % 6;

  if (comp != 2) {
    // ---- Q/K epilogue: 16-lane 32B-segment u16 stores ----
#pragma unroll
    for (int mt = 0; mt < 4; ++mt)
#pragma unroll
      for (int r = 0; r < 4; ++r) {
        int m = mb + wm + 16 * mt + 4 * lg + r;
        if (m >= MTOT) continue;
        int bb = m / NN, nn = m - bb * NN;
        int bh = bb * NH + h;
#pragma unroll
        for (int nt = 0; nt < 2; ++nt) {
          int d = wn + 16 * nt + lq;
          float v = acc[mt][nt][r];
          u16 hi, lo;
          if (comp == 0) {
            v *= SCALE_;
            split2(v, hi, lo);
            size_t a = ((size_t)bh * NKPAD + nn) * 64 + d;
            ws[OFF_QH + a] = hi;
            ws[OFF_QL + a] = lo;
          } else {
            split2(v, hi, lo);
            size_t a = ((size_t)bh * NKPAD + nn) * 64 + d;
            ws[OFF_KH + a] = hi;
            ws[OFF_KL + a] = lo;
          }
        }
      }
  } else {
    // ---- V epilogue: wave-private LDS transpose -> coalesced stores ----
    __syncthreads();                       // all waves past k-loop LDS reads
    u16* scr = LB + w * 2304;              // 32 rows x stride 72 (4608B/wave)
    const int mlane = mb + wm + l;
    const bool mv = mlane < MTOT;
    int bb = 0, nn = 0;
    if (mv) { bb = mlane / NN; nn = mlane - bb * NN; }
    const size_t vbase = (((size_t)(bb * NH + h) * 64 + wn)) * NKPAD + nn;

    for (int part = 0; part < 2; ++part) {
      u16* dst = ws + (part ? OFF_VTL : OFF_VTH);
#pragma unroll
      for (int nt = 0; nt < 2; ++nt)
#pragma unroll
        for (int mt = 0; mt < 4; ++mt) {
          ushort4 pk;
          u16 hi, lo;
          split2(acc[mt][nt][0], hi, lo); pk.x = part ? lo : hi;
          split2(acc[mt][nt][1], hi, lo); pk.y = part ? lo : hi;
          split2(acc[mt][nt][2], hi, lo); pk.z = part ? lo : hi;
          split2(acc[mt][nt][3], hi, lo); pk.w = part ? lo : hi;
          *(ushort4*)&scr[(16 * nt + lq) * 72 + 16 * mt + 4 * lg] = pk;
        }
      if (mv) {
        for (int i = 0; i < 32; ++i)
          dst[vbase + (size_t)i * NKPAD] = scr[i * 72 + l];
      }
    }
  }
#undef pASH
#undef pASL
}

// ---------------------------------------------------------------------------
// Flash attention v7 (unchanged): 128 q/block, 32 q/wave, dbuf K/V staging,
// register-pipelined mask/bias, P-hi only, setprio.
// ---------------------------------------------------------------------------
__global__ __launch_bounds__(256, 2) void attn_k(
    const u16* __restrict__ Qh, const u16* __restrict__ Ql,
    const u16* __restrict__ Kh, const u16* __restrict__ Kl,
    const u16* __restrict__ Vth, const u16* __restrict__ Vtl,
    const u16* __restrict__ btbl, const unsigned* __restrict__ pm,
    u16* __restrict__ Oh, u16* __restrict__ Ol)
{
  __shared__ u16 Kth[2][4096], Ktl[2][4096];
  __shared__ u16 Vsh[2][4096], Vsl[2][4096];
  __shared__ u16 Ph[4][2048];

  const int tid = threadIdx.x;
  const int w = tid >> 6, l = tid & 63, lq = l & 15, lg = l >> 4;
  const int q0 = blockIdx.x * 128;
  const int h = blockIdx.y, b = blockIdx.z;
  const int bh = b * NH + h;
  const int qr0 = q0 + 32 * w + lq;
  const int qr1 = qr0 + 16;
  const int swz = (lq & 7) << 3;
  const int ln8 = l >> 3, lc8 = l & 7;
  const int koff = ln8 * 64 + ((lc8 ^ ln8) << 3);
  const int voff = ln8 * NKPAD + ((lc8 ^ ln8) << 3);

#define STAGE(ch, bf)                                                        \
  {                                                                          \
    const int kb_ = (ch) * 64;                                               \
    const size_t kgb = ((size_t)bh * NKPAD + kb_ + 16 * w) * 64 + koff;      \
    const size_t vgb = ((size_t)bh * 64 + 16 * w) * NKPAD + kb_ + voff;      \
    gload16(&Kh[kgb],              &Kth[bf][(16 * w) * 64]);                 \
    gload16(&Kh[kgb + 512],        &Kth[bf][(16 * w + 8) * 64]);             \
    gload16(&Kl[kgb],              &Ktl[bf][(16 * w) * 64]);                 \
    gload16(&Kl[kgb + 512],        &Ktl[bf][(16 * w + 8) * 64]);             \
    gload16(&Vth[vgb],             &Vsh[bf][(16 * w) * 64]);                 \
    gload16(&Vth[vgb + 8 * NKPAD], &Vsh[bf][(16 * w + 8) * 64]);             \
    gload16(&Vtl[vgb],             &Vsl[bf][(16 * w) * 64]);                 \
    gload16(&Vtl[vgb + 8 * NKPAD], &Vsl[bf][(16 * w + 8) * 64]);             \
  }

  STAGE(0, 0);

  const size_t qb0 = ((size_t)bh * NKPAD + qr0) * 64 + 8 * lg;
  const size_t qb1 = ((size_t)bh * NKPAD + qr1) * 64 + 8 * lg;
  bf16x8 q0h[2], q0l[2], q1h[2], q1l[2];
  q0h[0] = *(const bf16x8*)&Qh[qb0];
  q0h[1] = *(const bf16x8*)&Qh[qb0 + 32];
  q0l[0] = *(const bf16x8*)&Ql[qb0];
  q0l[1] = *(const bf16x8*)&Ql[qb0 + 32];
  q1h[0] = *(const bf16x8*)&Qh[qb1];
  q1h[1] = *(const bf16x8*)&Qh[qb1 + 32];
  q1l[0] = *(const bf16x8*)&Ql[qb1];
  q1l[1] = *(const bf16x8*)&Ql[qb1 + 32];

  const int gq0 = (qr0 < NN) ? qr0 : NN - 1;
  const int gq1 = (qr1 < NN) ? qr1 : NN - 1;
  const bool qv0 = qr0 < NN, qv1 = qr1 < NN;
  const unsigned* pmrow0 = pm + ((size_t)b * NN + gq0) * 20;
  const unsigned* pmrow1 = pm + ((size_t)b * NN + gq1) * 20;
  const size_t brow0 = ((size_t)h * NN + gq0) * BSTRIDE;
  const size_t brow1 = ((size_t)h * NN + gq1) * BSTRIDE;

  uint2 cM0, cM1, nM0, nM1;
  uint2 cB0[4], cB1[4], nB0[4], nB1[4];
  cM0 = *(const uint2*)&pmrow0[0];
  cM1 = *(const uint2*)&pmrow1[0];
#pragma unroll
  for (int t = 0; t < 4; ++t) {
    int kkb = 16 * t + 4 * lg;
    cB0[t] = (qv0 && kkb <= 576) ? *(const uint2*)&btbl[brow0 + kkb]
                                 : make_uint2(0u, 0u);
    cB1[t] = (qv1 && kkb <= 576) ? *(const uint2*)&btbl[brow1 + kkb]
                                 : make_uint2(0u, 0u);
  }

  float m_reg0 = NEGBIG, l_reg0 = 0.f;
  float m_reg1 = NEGBIG, l_reg1 = 0.f;
  f32x4 accO0[4] = {}, accO1[4] = {};

  for (int ch = 0; ch < 10; ++ch) {
    const int bf = ch & 1;
    __syncthreads();
    if (ch < 9) {
      nM0 = *(const uint2*)&pmrow0[2 * (ch + 1)];
      nM1 = *(const uint2*)&pmrow1[2 * (ch + 1)];
      const int kb2 = (ch + 1) * 64;
#pragma unroll
      for (int t = 0; t < 4; ++t) {
        int kkb = kb2 + 16 * t + 4 * lg;
        nB0[t] = (qv0 && kkb <= 576) ? *(const uint2*)&btbl[brow0 + kkb]
                                     : make_uint2(0u, 0u);
        nB1[t] = (qv1 && kkb <= 576) ? *(const uint2*)&btbl[brow1 + kkb]
                                     : make_uint2(0u, 0u);
      }
      STAGE(ch + 1, bf ^ 1);
    }

    unsigned long long m64_0 = (unsigned long long)cM0.x |
                               ((unsigned long long)cM0.y << 32);
    unsigned long long m64_1 = (unsigned long long)cM1.x |
                               ((unsigned long long)cM1.y << 32);

    float sv0[4][4], sv1[4][4];
    __builtin_amdgcn_s_setprio(1);
#pragma unroll
    for (int t = 0; t < 4; ++t) {
      f32x4 a0, a1;
      a0[0] = bf2f((u16)(cB0[t].x & 0xffff));
      a0[1] = bf2f((u16)(cB0[t].x >> 16));
      a0[2] = bf2f((u16)(cB0[t].y & 0xffff));
      a0[3] = bf2f((u16)(cB0[t].y >> 16));
      a1[0] = bf2f((u16)(cB1[t].x & 0xffff));
      a1[1] = bf2f((u16)(cB1[t].x >> 16));
      a1[2] = bf2f((u16)(cB1[t].y & 0xffff));
      a1[3] = bf2f((u16)(cB1[t].y >> 16));
      const int ar = (16 * t + lq) * 64;
#pragma unroll
      for (int ks = 0; ks < 2; ++ks) {
        const int c = (8 * lg + 32 * ks) ^ swz;
        bf16x8 ah = *(const bf16x8*)&Kth[bf][ar + c];
        bf16x8 al = *(const bf16x8*)&Ktl[bf][ar + c];
        a0 = MFMA16(ah, q0h[ks], a0);
        a0 = MFMA16(ah, q0l[ks], a0);
        a0 = MFMA16(al, q0h[ks], a0);
        a1 = MFMA16(ah, q1h[ks], a1);
        a1 = MFMA16(ah, q1l[ks], a1);
        a1 = MFMA16(al, q1h[ks], a1);
      }
#pragma unroll
      for (int r = 0; r < 4; ++r) { sv0[t][r] = a0[r]; sv1[t][r] = a1[r]; }
    }
    __builtin_amdgcn_s_setprio(0);

    {
      float cmax = NEGBIG;
#pragma unroll
      for (int t = 0; t < 4; ++t)
#pragma unroll
        for (int r = 0; r < 4; ++r) {
          int kl = 16 * t + 4 * lg + r;
          float s = ((m64_0 >> kl) & 1ull) ? sv0[t][r] : NEGBIG;
          sv0[t][r] = s;
          cmax = fmaxf(cmax, s);
        }
      cmax = fmaxf(cmax, __shfl_xor(cmax, 16));
      cmax = fmaxf(cmax, __shfl_xor(cmax, 32));
      float m_new = fmaxf(m_reg0, cmax);
      float fx = __expf(m_reg0 - m_new);
      float csum = 0.f;
#pragma unroll
      for (int t = 0; t < 4; ++t) {
        float e0 = __expf(sv0[t][0] - m_new);
        float e1 = __expf(sv0[t][1] - m_new);
        float e2 = __expf(sv0[t][2] - m_new);
        float e3 = __expf(sv0[t][3] - m_new);
        csum += e0 + e1 + e2 + e3;
        ushort4 ph;
        ph.x = f2bf(e0); ph.y = f2bf(e1); ph.z = f2bf(e2); ph.w = f2bf(e3);
        *(ushort4*)&Ph[w][lq * 64 + ((16 * t + 4 * lg) ^ swz)] = ph;
      }
      csum += __shfl_xor(csum, 16);
      csum += __shfl_xor(csum, 32);
      l_reg0 = l_reg0 * fx + csum;
      m_reg0 = m_new;
      float fxr[4];
#pragma unroll
      for (int r = 0; r < 4; ++r) fxr[r] = __shfl(fx, 4 * lg + r);
#pragma unroll
      for (int t = 0; t < 4; ++t) {
        accO0[t][0] *= fxr[0]; accO0[t][1] *= fxr[1];
        accO0[t][2] *= fxr[2]; accO0[t][3] *= fxr[3];
      }
    }
    {
      float cmax = NEGBIG;
#pragma unroll
      for (int t = 0; t < 4; ++t)
#pragma unroll
        for (int r = 0; r < 4; ++r) {
          int kl = 16 * t + 4 * lg + r;
          float s = ((m64_1 >> kl) & 1ull) ? sv1[t][r] : NEGBIG;
          sv1[t][r] = s;
          cmax = fmaxf(cmax, s);
        }
      cmax = fmaxf(cmax, __shfl_xor(cmax, 16));
      cmax = fmaxf(cmax, __shfl_xor(cmax, 32));
      float m_new = fmaxf(m_reg1, cmax);
      float fx = __expf(m_reg1 - m_new);
      float csum = 0.f;
#pragma unroll
      for (int t = 0; t < 4; ++t) {
        float e0 = __expf(sv1[t][0] - m_new);
        float e1 = __expf(sv1[t][1] - m_new);
        float e2 = __expf(sv1[t][2] - m_new);
        float e3 = __expf(sv1[t][3] - m_new);
        csum += e0 + e1 + e2 + e3;
        ushort4 ph;
        ph.x = f2bf(e0); ph.y = f2bf(e1); ph.z = f2bf(e2); ph.w = f2bf(e3);
        *(ushort4*)&Ph[w][(16 + lq) * 64 + ((16 * t + 4 * lg) ^ swz)] = ph;
      }
      csum += __shfl_xor(csum, 16);
      csum += __shfl_xor(csum, 32);
      l_reg1 = l_reg1 * fx + csum;
      m_reg1 = m_new;
      float fxr[4];
#pragma unroll
      for (int r = 0; r < 4; ++r) fxr[r] = __shfl(fx, 4 * lg + r);
#pragma unroll
      for (int t = 0; t < 4; ++t) {
        accO1[t][0] *= fxr[0]; accO1[t][1] *= fxr[1];
        accO1[t][2] *= fxr[2]; accO1[t][3] *= fxr[3];
      }
    }

    bf16x8 pa0[2], pa1[2];
#pragma unroll
    for (int ks = 0; ks < 2; ++ks) {
      int c = (8 * lg + 32 * ks) ^ swz;
      pa0[ks] = *(const bf16x8*)&Ph[w][lq * 64 + c];
      pa1[ks] = *(const bf16x8*)&Ph[w][(16 + lq) * 64 + c];
    }

    __builtin_amdgcn_s_setprio(1);
#pragma unroll
    for (int t = 0; t < 4; ++t) {
      const int vr = (16 * t + lq) * 64;
#pragma unroll
      for (int ks = 0; ks < 2; ++ks) {
        const int c = (8 * lg + 32 * ks) ^ swz;
        bf16x8 vh = *(const bf16x8*)&Vsh[bf][vr + c];
        bf16x8 vl = *(const bf16x8*)&Vsl[bf][vr + c];
        accO0[t] = MFMA16(pa0[ks], vh, accO0[t]);
        accO0[t] = MFMA16(pa0[ks], vl, accO0[t]);
        accO1[t] = MFMA16(pa1[ks], vh, accO1[t]);
        accO1[t] = MFMA16(pa1[ks], vl, accO1[t]);
      }
    }
    __builtin_amdgcn_s_setprio(0);

    if (ch < 9) {
      cM0 = nM0; cM1 = nM1;
#pragma unroll
      for (int t = 0; t < 4; ++t) { cB0[t] = nB0[t]; cB1[t] = nB1[t]; }
    }
  }
#undef STAGE

  float il0 = 1.f / l_reg0;
  float il1 = 1.f / l_reg1;
  float ilr0[4], ilr1[4];
#pragma unroll
  for (int r = 0; r < 4; ++r) {
    ilr0[r] = __shfl(il0, 4 * lg + r);
    ilr1[r] = __shfl(il1, 4 * lg + r);
  }
#pragma unroll
  for (int t = 0; t < 4; ++t)
#pragma unroll
    for (int r = 0; r < 4; ++r) {
      int g0 = q0 + 32 * w + 4 * lg + r;
      if (g0 < NN) {
        float v = accO0[t][r] * ilr0[r];
        u16 hi, lo;
        split2(v, hi, lo);
        size_t a = ((size_t)b * NN + g0) * NC + h * 64 + 16 * t + lq;
        Oh[a] = hi;
        Ol[a] = lo;
      }
      int g1 = g0 + 16;
      if (g1 < NN) {
        float v = accO1[t][r] * ilr1[r];
        u16 hi, lo;
        split2(v, hi, lo);
        size_t a = ((size_t)b * NN + g1) * NC + h * 64 + 16 * t + lq;
        Oh[a] = hi;
        Ol[a] = lo;
      }
    }
}

// ---------------------------------------------------------------------------
// Projection GEMM v8: triple-buffer single-barrier ledger schedule
// (S-group=2, B-group=4 -> waits a:6, d:8; tails 6/4/0). fp32 output.
// ---------------------------------------------------------------------------
__global__ __launch_bounds__(256, 3) void proj_mfma_k(
    const u16* __restrict__ Ah, const u16* __restrict__ Al,
    const u16* __restrict__ Wh, const u16* __restrict__ Wl,
    const float* __restrict__ bias, float* __restrict__ out)
{
  __shared__ u16 Ash[3][2048], Asl[3][2048];   // [64][32] per buffer

  const int tid = threadIdx.x;
  const int w = tid >> 6, l = tid & 63, lq = l & 15, lg = l >> 4;
  const int wm = (w >> 1) * 32, wn = (w & 1) * 32;
  const int mb = blockIdx.x * 64;
  const int rb = blockIdx.y * 64;
  const int r0 = rb + wn;
  const int soff = (l >> 2) * 384 + (l & 3) * 8;

#define STAGE_A(k0_, bf_)                                                    \
  {                                                                          \
    const int tr = 16 * w;                                                   \
    const size_t ga = (size_t)(mb + tr) * 384 + (k0_) + soff;                \
    gload16(&Ah[ga], &Ash[bf_][tr * 32]);                                    \
    gload16(&Al[ga], &Asl[bf_][tr * 32]);                                    \
  }

  const size_t brow = (size_t)(r0 + lq) * 384 + 8 * lg;
#define BLOAD(k0_, BH_, BL_)                                                 \
  {                                                                          \
    _Pragma("unroll")                                                        \
    for (int nt = 0; nt < 2; ++nt) {                                         \
      BH_[nt] = *(const bf16x8*)&Wh[brow + (size_t)(16 * nt) * 384 + (k0_)]; \
      BL_[nt] = *(const bf16x8*)&Wl[brow + (size_t)(16 * nt) * 384 + (k0_)]; \
    }                                                                        \
  }

#define COMPUTE(bf_, BH_, BL_)                                               \
  {                                                                          \
    _Pragma("unroll")                                                        \
    for (int mt = 0; mt < 2; ++mt) {                                         \
      bf16x8 ah = *(const bf16x8*)&Ash[bf_][(wm + 16 * mt + lq) * 32 + 8 * lg]; \
      bf16x8 al = *(const bf16x8*)&Asl[bf_][(wm + 16 * mt + lq) * 32 + 8 * lg]; \
      _Pragma("unroll")                                                      \
      for (int nt = 0; nt < 2; ++nt) {                                       \
        acc[mt][nt] = MFMA16(ah, BH_[nt], acc[mt][nt]);                      \
        acc[mt][nt] = MFMA16(ah, BL_[nt], acc[mt][nt]);                      \
        acc[mt][nt] = MFMA16(al, BH_[nt], acc[mt][nt]);                      \
      }                                                                      \
    }                                                                        \
  }

  bf16x8 bh2[2][2], bl2[2][2];
  STAGE_A(0, 0);
  BLOAD(0, bh2[0], bl2[0]);
  STAGE_A(32, 1);

  f32x4 acc[2][2];
#pragma unroll
  for (int nt = 0; nt < 2; ++nt) {
    float bv = bias[r0 + 16 * nt + lq];
#pragma unroll
    for (int mt = 0; mt < 2; ++mt) acc[mt][nt] = (f32x4){bv, bv, bv, bv};
  }

#pragma unroll
  for (int k = 0; k < 12; ++k) {
    if (k < 11) { asm volatile("s_waitcnt vmcnt(6)" ::: "memory"); }
    else        { asm volatile("s_waitcnt vmcnt(4)" ::: "memory"); }
    SB0();
    __builtin_amdgcn_s_barrier();
    SB0();
    if (k < 11) BLOAD(32 * (k + 1), bh2[(k + 1) & 1], bl2[(k + 1) & 1]);
    if (k < 10) STAGE_A(32 * (k + 2), (k + 2) % 3);
    SB0();
    if (k < 10)      { asm volatile("s_waitcnt vmcnt(8)" ::: "memory"); }
    else if (k == 10){ asm volatile("s_waitcnt vmcnt(6)" ::: "memory"); }
    else             { asm volatile("s_waitcnt vmcnt(0)" ::: "memory"); }
    SB0();
    COMPUTE(k % 3, bh2[k & 1], bl2[k & 1]);
  }

#undef COMPUTE
#undef BLOAD
#undef STAGE_A

#pragma unroll
  for (int mt = 0; mt < 2; ++mt)
#pragma unroll
    for (int r = 0; r < 4; ++r) {
      int m = mb + wm + 16 * mt + 4 * lg + r;
      if (m >= MTOT) continue;
#pragma unroll
      for (int nt = 0; nt < 2; ++nt)
        out[(size_t)m * NC + r0 + 16 * nt + lq] = acc[mt][nt][r];
    }
}

// ---------------------------------------------------------------------------
extern "C" void kernel_launch(void* const* d_in, const int* in_sizes, int n_in,
                              void* d_out, int out_size, void* d_ws, size_t ws_size,
                              hipStream_t stream) {
  const float* x       = (const float*)d_in[0];
  const float* qkv_w   = (const float*)d_in[1];
  const float* qkv_b   = (const float*)d_in[2];
  const float* proj_w  = (const float*)d_in[3];
  const float* proj_b  = (const float*)d_in[4];
  const float* rel_pos = (const float*)d_in[5];
  const int*   rel_idx = (const int*)d_in[6];
  const int*   mask    = (const int*)d_in[7];
  const int*   patch   = (const int*)d_in[8];
  float* out = (float*)d_out;
  u16* W16 = (u16*)d_ws;

  unsigned* pmp = (unsigned*)(W16 + OFF_PM);
  u16* btblp = W16 + OFF_BT;

  prep_k<<<4080, 256, 0, stream>>>(x, qkv_w, proj_w, W16);
  qkv_mfma_k<<<7084, 256, 0, stream>>>(
      W16 + OFF_XH, W16 + OFF_XL, W16 + OFF_WQH, W16 + OFF_WQL, qkv_b,
      mask, rel_pos, rel_idx, patch, W16);
  attn_k<<<dim3(5, NH, NB), 256, 0, stream>>>(
      W16 + OFF_QH, W16 + OFF_QL, W16 + OFF_KH, W16 + OFF_KL,
      W16 + OFF_VTH, W16 + OFF_VTL, btblp, pmp,
      W16 + OFF_XH, W16 + OFF_XL);
  proj_mfma_k<<<dim3(146, 6), 256, 0, stream>>>(
      W16 + OFF_XH, W16 + OFF_XL, W16 + OFF_WPH, W16 + OFF_WPL, proj_b, out);
}

// Round 16
// 145.789 us; speedup vs baseline: 1.0687x; 1.0687x over previous
//
#include <hip/hip_runtime.h>
#include <float.h>
#include <math.h>

#define NB 16
#define NN 577
#define NC 384
#define NH 6
#define ND 64
#define RPD2 2209
#define MTOT 9232
#define MPAD 9344
#define SCALE_ 0.125f
#define NEGBIG -3.0e38f
#define BSTRIDE 580
#define NKPAD 640

typedef __attribute__((ext_vector_type(8))) short bf16x8;
typedef __attribute__((ext_vector_type(4))) float f32x4;
typedef unsigned short u16;

#define MFMA16(a, b, c) __builtin_amdgcn_mfma_f32_16x16x32_bf16(a, b, c, 0, 0, 0)

// workspace offsets in u16 units
#define SQA 3932160ull                    // 96*640*64
#define OFF_QH 0ull
#define OFF_QL SQA
#define OFF_KH (2ull * SQA)
#define OFF_KL (3ull * SQA)
#define OFF_VTH (4ull * SQA)
#define OFF_VTL (5ull * SQA)
#define OFF_XH (6ull * SQA)               // aliased as Oh after qkv
#define OFF_XL (6ull * SQA + 3588096ull)  // aliased as Ol
#define OFF_WQH (6ull * SQA + 2ull * 3588096ull)
#define OFF_WQL (OFF_WQH + 442368ull)
#define OFF_WPH (OFF_WQL + 442368ull)
#define OFF_WPL (OFF_WPH + 147456ull)
#define OFF_BT  (OFF_WPL + 147456ull)
#define OFF_PM  (OFF_BT + 2007960ull)     // u32 region, 8B-aligned

static __device__ __forceinline__ u16 f2bf(float f) {
  unsigned u = __float_as_uint(f);
  u += 0x7fff + ((u >> 16) & 1);
  return (u16)(u >> 16);
}
static __device__ __forceinline__ float bf2f(u16 h) {
  return __uint_as_float((unsigned)h << 16);
}
static __device__ __forceinline__ void split2(float v, u16& hi, u16& lo) {
  hi = f2bf(v);
  lo = f2bf(v - bf2f(hi));
}
static __device__ __forceinline__ void gload16(const void* g, void* l) {
  __builtin_amdgcn_global_load_lds(
      (const __attribute__((address_space(1))) void*)g,
      (__attribute__((address_space(3))) void*)l, 16, 0, 0);
}
#define SB0() __builtin_amdgcn_sched_barrier(0)

// ---------------------------------------------------------------------------
// Fused prep: split inputs (blocks 0..4079), pack mask (4080..6387),
// bias table (6388..9849).
// ---------------------------------------------------------------------------
__global__ __launch_bounds__(256) void prep_k(
    const float* __restrict__ x, const float* __restrict__ wq,
    const float* __restrict__ wp, const int* __restrict__ mask,
    const float* __restrict__ rel_pos, const int* __restrict__ rel_idx,
    const int* __restrict__ patch, u16* __restrict__ ws)
{
  const int bidx = blockIdx.x;
  const int tid = threadIdx.x;

  if (bidx < 4080) {                       // ---- split fp32 -> bf16 hi/lo ----
    const int q = bidx * 256 + tid;
    float4 v = {0.f, 0.f, 0.f, 0.f};
    u16 *dh, *dl;
    if (q < 897024) {
      if (q < 886272) v = ((const float4*)x)[q];
      dh = ws + OFF_XH + 4ull * q;
      dl = ws + OFF_XL + 4ull * q;
    } else if (q < 1007616) {
      int t = q - 897024;
      v = ((const float4*)wq)[t];
      dh = ws + OFF_WQH + 4ull * t;
      dl = ws + OFF_WQL + 4ull * t;
    } else {
      int t = q - 1007616;
      v = ((const float4*)wp)[t];
      dh = ws + OFF_WPH + 4ull * t;
      dl = ws + OFF_WPL + 4ull * t;
    }
    ushort4 hh, ll;
    split2(v.x, hh.x, ll.x);
    split2(v.y, hh.y, ll.y);
    split2(v.z, hh.z, ll.z);
    split2(v.w, hh.w, ll.w);
    *(ushort4*)dh = hh;
    *(ushort4*)dl = ll;
  } else if (bidx < 6388) {                // ---- pack mask -> bitmask ----
    unsigned* pm = (unsigned*)(ws + OFF_PM);
    const int pbid = bidx - 4080;
    const int wid = (pbid * 256 + tid) >> 6;
    const int lane = tid & 63;
    if (wid >= MTOT) return;
    const int* mr = mask + (size_t)wid * NN;
#pragma unroll
    for (int c = 0; c < 10; ++c) {
      int k = c * 64 + lane;
      int v = (k < NN) ? mr[k] : 0;
      unsigned long long bal = __ballot(v != 0);
      if (lane == 0) pm[wid * 20 + 2 * c] = (unsigned)bal;
      if (lane == 1) pm[wid * 20 + 2 * c + 1] = (unsigned)(bal >> 32);
    }
  } else {                                 // ---- bias table ----
    const int f = bidx - 6388;             // 0..3461
    const int q = f % NN, h = f / NN;
    const int pa = *patch;
    u16* row = ws + OFF_BT + ((size_t)h * NN + q) * BSTRIDE;
    for (int kk = tid; kk < BSTRIDE; kk += 256) {
      float v = 0.f;
      if (pa && q >= 1 && kk >= 1 && kk < NN)
        v = rel_pos[h * RPD2 + rel_idx[(q - 1) * 576 + (kk - 1)]];
      row[kk] = f2bf(v);
    }
  }
}

// ---------------------------------------------------------------------------
// QKV GEMM v6s: R11's best-measured structure + 4-slot XOR swizzle on the
// A-tile (staging source pre-swizzled, reads XOR'd) to cut the ds_read_b128
// bank conflict from 8-way to 4-way.
// ---------------------------------------------------------------------------
__global__ __launch_bounds__(256, 3) void qkv_mfma_k(
    const u16* __restrict__ Xh, const u16* __restrict__ Xl,
    const u16* __restrict__ Wh, const u16* __restrict__ Wl,
    const float* __restrict__ bias, u16* __restrict__ ws)
{
  __shared__ u16 LB[16384];                // 32KB: A hi 2 bufs, A lo 2 bufs

#define pASH(bf) (LB + (bf) * 4096)
#define pASL(bf) (LB + 8192 + (bf) * 4096)

  const int tid = threadIdx.x;
  const int w = tid >> 6, l = tid & 63, lq = l & 15, lg = l >> 4;
  const int wm = (w >> 1) * 64, wn = (w & 1) * 64;

  // XCD-chunked bijective decode (657 = 8*82 + 1), rb-fastest within chunk.
  const int o = blockIdx.x;
  const int xcd = o & 7, rank = o >> 3;
  const int wg = (xcd == 0) ? rank : (83 + (xcd - 1) * 82 + rank);
  const int mb = (wg / 9) * 128;
  const int rb = (wg % 9) * 128;
  const int r0 = rb + wn;
  // staging source offset with slot XOR (row within 16-row group = l>>2;
  // row&3 == (l>>2)&3 since all tile-row bases are multiples of 16)
  const int soff = (l >> 2) * 384 + (((l & 3) ^ ((l >> 2) & 3)) << 3);
  // read-side swizzled column (row&3 == lq&3)
  const int csw = (lg ^ (lq & 3)) << 3;

#define STAGE_A(k0_, bf_)                                                    \
  {                                                                          \
    _Pragma("unroll")                                                        \
    for (int j = 0; j < 2; ++j) {                                            \
      const int tr = 32 * w + 16 * j;                                        \
      const size_t ga = (size_t)(mb + tr) * 384 + (k0_) + soff;              \
      gload16(&Xh[ga], pASH(bf_) + tr * 32);                                 \
      gload16(&Xl[ga], pASL(bf_) + tr * 32);                                 \
    }                                                                        \
  }

  const size_t brow = (size_t)(r0 + lq) * 384 + 8 * lg;
#define BLOAD(k0_, BH_, BL_)                                                 \
  {                                                                          \
    _Pragma("unroll")                                                        \
    for (int nt = 0; nt < 4; ++nt) {                                         \
      BH_[nt] = *(const bf16x8*)&Wh[brow + (size_t)(16 * nt) * 384 + (k0_)]; \
      BL_[nt] = *(const bf16x8*)&Wl[brow + (size_t)(16 * nt) * 384 + (k0_)]; \
    }                                                                        \
  }

#define COMPUTE(bf_)                                                         \
  {                                                                          \
    _Pragma("unroll")                                                        \
    for (int mt = 0; mt < 4; ++mt) {                                         \
      bf16x8 ah = *(const bf16x8*)(pASH(bf_) + (wm + 16 * mt + lq) * 32 + csw); \
      bf16x8 al = *(const bf16x8*)(pASL(bf_) + (wm + 16 * mt + lq) * 32 + csw); \
      _Pragma("unroll")                                                      \
      for (int nt = 0; nt < 4; ++nt) {                                       \
        acc[mt][nt] = MFMA16(ah, bhf[nt], acc[mt][nt]);                      \
        acc[mt][nt] = MFMA16(ah, blf[nt], acc[mt][nt]);                      \
        acc[mt][nt] = MFMA16(al, bhf[nt], acc[mt][nt]);                      \
      }                                                                      \
    }                                                                        \
  }

  bf16x8 bhf[4], blf[4], nbh[4], nbl[4];
  BLOAD(0, bhf, blf);
  STAGE_A(0, 0);
  STAGE_A(32, 1);

  f32x4 acc[4][4];
#pragma unroll
  for (int nt = 0; nt < 4; ++nt) {
    float bv = bias[r0 + 16 * nt + lq];
#pragma unroll
    for (int mt = 0; mt < 4; ++mt) acc[mt][nt] = (f32x4){bv, bv, bv, bv};
  }

  for (int k = 0; k < 11; ++k) {
    asm volatile("s_waitcnt vmcnt(4)" ::: "memory");
    SB0();
    __builtin_amdgcn_s_barrier();
    SB0();
    const int bfb = k & 1;
    COMPUTE(bfb);
    SB0();
    __builtin_amdgcn_s_barrier();
    SB0();
    BLOAD(32 * (k + 1), nbh, nbl);
    if (k < 10) STAGE_A(32 * (k + 2), bfb);
#pragma unroll
    for (int nt = 0; nt < 4; ++nt) { bhf[nt] = nbh[nt]; blf[nt] = nbl[nt]; }
  }
  asm volatile("s_waitcnt vmcnt(0)" ::: "memory");
  SB0();
  __builtin_amdgcn_s_barrier();
  SB0();
  COMPUTE(1);

#undef COMPUTE
#undef BLOAD
#undef STAGE_A

  const int comp = rb / 384;               // block-uniform
  const int h = ((rb % 384) + wn) >> 6;

  if (comp != 2) {
    // ---- Q/K epilogue: 16-lane 32B-segment u16 stores ----
#pragma unroll
    for (int mt = 0; mt < 4; ++mt)
#pragma unroll
      for (int r = 0; r < 4; ++r) {
        int m = mb + wm + 16 * mt + 4 * lg + r;
        if (m >= MTOT) continue;
        int bb = m / NN, nn = m - bb * NN;
        int bh = bb * NH + h;
#pragma unroll
        for (int nt = 0; nt < 4; ++nt) {
          int d = 16 * nt + lq;
          float v = acc[mt][nt][r];
          u16 hi, lo;
          if (comp == 0) {
            v *= SCALE_;
            split2(v, hi, lo);
            size_t a = ((size_t)bh * NKPAD + nn) * 64 + d;
            ws[OFF_QH + a] = hi;
            ws[OFF_QL + a] = lo;
          } else {
            split2(v, hi, lo);
            size_t a = ((size_t)bh * NKPAD + nn) * 64 + d;
            ws[OFF_KH + a] = hi;
            ws[OFF_KL + a] = lo;
          }
        }
      }
  } else {
    // ---- V epilogue: transpose via wave-private LDS scratch, then
    //      fully-coalesced per-d-row stores ----
    __syncthreads();                       // all waves past the k-loop LDS reads
    u16* scr = LB + w * 2304;              // 32 rows x stride 72, 4608B/wave
    const int mlane = mb + wm + l;
    const bool mv = mlane < MTOT;
    int bb = 0, nn = 0;
    if (mv) { bb = mlane / NN; nn = mlane - bb * NN; }
    const size_t vbase = ((size_t)(bb * NH + h) * 64) * NKPAD + nn;

    for (int part = 0; part < 2; ++part) {
      u16* dst = ws + (part ? OFF_VTL : OFF_VTH);
      for (int dh2 = 0; dh2 < 2; ++dh2) {
#pragma unroll
        for (int nt2 = 0; nt2 < 2; ++nt2) {
          const int nt = 2 * dh2 + nt2;
#pragma unroll
          for (int mt = 0; mt < 4; ++mt) {
            ushort4 pk;
            u16 hi, lo;
            split2(acc[mt][nt][0], hi, lo); pk.x = part ? lo : hi;
            split2(acc[mt][nt][1], hi, lo); pk.y = part ? lo : hi;
            split2(acc[mt][nt][2], hi, lo); pk.z = part ? lo : hi;
            split2(acc[mt][nt][3], hi, lo); pk.w = part ? lo : hi;
            *(ushort4*)&scr[(16 * nt2 + lq) * 72 + 16 * mt + 4 * lg] = pk;
          }
        }
        if (mv) {
          for (int i = 0; i < 32; ++i) {
            const int d = 32 * dh2 + i;
            dst[vbase + (size_t)d * NKPAD] = scr[i * 72 + l];
          }
        }
      }
    }
  }
#undef pASH
#undef pASL
}

// ---------------------------------------------------------------------------
// Flash attention v7 (unchanged): 128 q/block, 32 q/wave, dbuf K/V staging,
// register-pipelined mask/bias, P-hi only, setprio.
// ---------------------------------------------------------------------------
__global__ __launch_bounds__(256, 2) void attn_k(
    const u16* __restrict__ Qh, const u16* __restrict__ Ql,
    const u16* __restrict__ Kh, const u16* __restrict__ Kl,
    const u16* __restrict__ Vth, const u16* __restrict__ Vtl,
    const u16* __restrict__ btbl, const unsigned* __restrict__ pm,
    u16* __restrict__ Oh, u16* __restrict__ Ol)
{
  __shared__ u16 Kth[2][4096], Ktl[2][4096];
  __shared__ u16 Vsh[2][4096], Vsl[2][4096];
  __shared__ u16 Ph[4][2048];

  const int tid = threadIdx.x;
  const int w = tid >> 6, l = tid & 63, lq = l & 15, lg = l >> 4;
  const int q0 = blockIdx.x * 128;
  const int h = blockIdx.y, b = blockIdx.z;
  const int bh = b * NH + h;
  const int qr0 = q0 + 32 * w + lq;
  const int qr1 = qr0 + 16;
  const int swz = (lq & 7) << 3;
  const int ln8 = l >> 3, lc8 = l & 7;
  const int koff = ln8 * 64 + ((lc8 ^ ln8) << 3);
  const int voff = ln8 * NKPAD + ((lc8 ^ ln8) << 3);

#define STAGE(ch, bf)                                                        \
  {                                                                          \
    const int kb_ = (ch) * 64;                                               \
    const size_t kgb = ((size_t)bh * NKPAD + kb_ + 16 * w) * 64 + koff;      \
    const size_t vgb = ((size_t)bh * 64 + 16 * w) * NKPAD + kb_ + voff;      \
    gload16(&Kh[kgb],              &Kth[bf][(16 * w) * 64]);                 \
    gload16(&Kh[kgb + 512],        &Kth[bf][(16 * w + 8) * 64]);             \
    gload16(&Kl[kgb],              &Ktl[bf][(16 * w) * 64]);                 \
    gload16(&Kl[kgb + 512],        &Ktl[bf][(16 * w + 8) * 64]);             \
    gload16(&Vth[vgb],             &Vsh[bf][(16 * w) * 64]);                 \
    gload16(&Vth[vgb + 8 * NKPAD], &Vsh[bf][(16 * w + 8) * 64]);             \
    gload16(&Vtl[vgb],             &Vsl[bf][(16 * w) * 64]);                 \
    gload16(&Vtl[vgb + 8 * NKPAD], &Vsl[bf][(16 * w + 8) * 64]);             \
  }

  STAGE(0, 0);

  const size_t qb0 = ((size_t)bh * NKPAD + qr0) * 64 + 8 * lg;
  const size_t qb1 = ((size_t)bh * NKPAD + qr1) * 64 + 8 * lg;
  bf16x8 q0h[2], q0l[2], q1h[2], q1l[2];
  q0h[0] = *(const bf16x8*)&Qh[qb0];
  q0h[1] = *(const bf16x8*)&Qh[qb0 + 32];
  q0l[0] = *(const bf16x8*)&Ql[qb0];
  q0l[1] = *(const bf16x8*)&Ql[qb0 + 32];
  q1h[0] = *(const bf16x8*)&Qh[qb1];
  q1h[1] = *(const bf16x8*)&Qh[qb1 + 32];
  q1l[0] = *(const bf16x8*)&Ql[qb1];
  q1l[1] = *(const bf16x8*)&Ql[qb1 + 32];

  const int gq0 = (qr0 < NN) ? qr0 : NN - 1;
  const int gq1 = (qr1 < NN) ? qr1 : NN - 1;
  const bool qv0 = qr0 < NN, qv1 = qr1 < NN;
  const unsigned* pmrow0 = pm + ((size_t)b * NN + gq0) * 20;
  const unsigned* pmrow1 = pm + ((size_t)b * NN + gq1) * 20;
  const size_t brow0 = ((size_t)h * NN + gq0) * BSTRIDE;
  const size_t brow1 = ((size_t)h * NN + gq1) * BSTRIDE;

  uint2 cM0, cM1, nM0, nM1;
  uint2 cB0[4], cB1[4], nB0[4], nB1[4];
  cM0 = *(const uint2*)&pmrow0[0];
  cM1 = *(const uint2*)&pmrow1[0];
#pragma unroll
  for (int t = 0; t < 4; ++t) {
    int kkb = 16 * t + 4 * lg;
    cB0[t] = (qv0 && kkb <= 576) ? *(const uint2*)&btbl[brow0 + kkb]
                                 : make_uint2(0u, 0u);
    cB1[t] = (qv1 && kkb <= 576) ? *(const uint2*)&btbl[brow1 + kkb]
                                 : make_uint2(0u, 0u);
  }

  float m_reg0 = NEGBIG, l_reg0 = 0.f;
  float m_reg1 = NEGBIG, l_reg1 = 0.f;
  f32x4 accO0[4] = {}, accO1[4] = {};

  for (int ch = 0; ch < 10; ++ch) {
    const int bf = ch & 1;
    __syncthreads();
    if (ch < 9) {
      nM0 = *(const uint2*)&pmrow0[2 * (ch + 1)];
      nM1 = *(const uint2*)&pmrow1[2 * (ch + 1)];
      const int kb2 = (ch + 1) * 64;
#pragma unroll
      for (int t = 0; t < 4; ++t) {
        int kkb = kb2 + 16 * t + 4 * lg;
        nB0[t] = (qv0 && kkb <= 576) ? *(const uint2*)&btbl[brow0 + kkb]
                                     : make_uint2(0u, 0u);
        nB1[t] = (qv1 && kkb <= 576) ? *(const uint2*)&btbl[brow1 + kkb]
                                     : make_uint2(0u, 0u);
      }
      STAGE(ch + 1, bf ^ 1);
    }

    unsigned long long m64_0 = (unsigned long long)cM0.x |
                               ((unsigned long long)cM0.y << 32);
    unsigned long long m64_1 = (unsigned long long)cM1.x |
                               ((unsigned long long)cM1.y << 32);

    float sv0[4][4], sv1[4][4];
    __builtin_amdgcn_s_setprio(1);
#pragma unroll
    for (int t = 0; t < 4; ++t) {
      f32x4 a0, a1;
      a0[0] = bf2f((u16)(cB0[t].x & 0xffff));
      a0[1] = bf2f((u16)(cB0[t].x >> 16));
      a0[2] = bf2f((u16)(cB0[t].y & 0xffff));
      a0[3] = bf2f((u16)(cB0[t].y >> 16));
      a1[0] = bf2f((u16)(cB1[t].x & 0xffff));
      a1[1] = bf2f((u16)(cB1[t].x >> 16));
      a1[2] = bf2f((u16)(cB1[t].y & 0xffff));
      a1[3] = bf2f((u16)(cB1[t].y >> 16));
      const int ar = (16 * t + lq) * 64;
#pragma unroll
      for (int ks = 0; ks < 2; ++ks) {
        const int c = (8 * lg + 32 * ks) ^ swz;
        bf16x8 ah = *(const bf16x8*)&Kth[bf][ar + c];
        bf16x8 al = *(const bf16x8*)&Ktl[bf][ar + c];
        a0 = MFMA16(ah, q0h[ks], a0);
        a0 = MFMA16(ah, q0l[ks], a0);
        a0 = MFMA16(al, q0h[ks], a0);
        a1 = MFMA16(ah, q1h[ks], a1);
        a1 = MFMA16(ah, q1l[ks], a1);
        a1 = MFMA16(al, q1h[ks], a1);
      }
#pragma unroll
      for (int r = 0; r < 4; ++r) { sv0[t][r] = a0[r]; sv1[t][r] = a1[r]; }
    }
    __builtin_amdgcn_s_setprio(0);

    {
      float cmax = NEGBIG;
#pragma unroll
      for (int t = 0; t < 4; ++t)
#pragma unroll
        for (int r = 0; r < 4; ++r) {
          int kl = 16 * t + 4 * lg + r;
          float s = ((m64_0 >> kl) & 1ull) ? sv0[t][r] : NEGBIG;
          sv0[t][r] = s;
          cmax = fmaxf(cmax, s);
        }
      cmax = fmaxf(cmax, __shfl_xor(cmax, 16));
      cmax = fmaxf(cmax, __shfl_xor(cmax, 32));
      float m_new = fmaxf(m_reg0, cmax);
      float fx = __expf(m_reg0 - m_new);
      float csum = 0.f;
#pragma unroll
      for (int t = 0; t < 4; ++t) {
        float e0 = __expf(sv0[t][0] - m_new);
        float e1 = __expf(sv0[t][1] - m_new);
        float e2 = __expf(sv0[t][2] - m_new);
        float e3 = __expf(sv0[t][3] - m_new);
        csum += e0 + e1 + e2 + e3;
        ushort4 ph;
        ph.x = f2bf(e0); ph.y = f2bf(e1); ph.z = f2bf(e2); ph.w = f2bf(e3);
        *(ushort4*)&Ph[w][lq * 64 + ((16 * t + 4 * lg) ^ swz)] = ph;
      }
      csum += __shfl_xor(csum, 16);
      csum += __shfl_xor(csum, 32);
      l_reg0 = l_reg0 * fx + csum;
      m_reg0 = m_new;
      float fxr[4];
#pragma unroll
      for (int r = 0; r < 4; ++r) fxr[r] = __shfl(fx, 4 * lg + r);
#pragma unroll
      for (int t = 0; t < 4; ++t) {
        accO0[t][0] *= fxr[0]; accO0[t][1] *= fxr[1];
        accO0[t][2] *= fxr[2]; accO0[t][3] *= fxr[3];
      }
    }
    {
      float cmax = NEGBIG;
#pragma unroll
      for (int t = 0; t < 4; ++t)
#pragma unroll
        for (int r = 0; r < 4; ++r) {
          int kl = 16 * t + 4 * lg + r;
          float s = ((m64_1 >> kl) & 1ull) ? sv1[t][r] : NEGBIG;
          sv1[t][r] = s;
          cmax = fmaxf(cmax, s);
        }
      cmax = fmaxf(cmax, __shfl_xor(cmax, 16));
      cmax = fmaxf(cmax, __shfl_xor(cmax, 32));
      float m_new = fmaxf(m_reg1, cmax);
      float fx = __expf(m_reg1 - m_new);
      float csum = 0.f;
#pragma unroll
      for (int t = 0; t < 4; ++t) {
        float e0 = __expf(sv1[t][0] - m_new);
        float e1 = __expf(sv1[t][1] - m_new);
        float e2 = __expf(sv1[t][2] - m_new);
        float e3 = __expf(sv1[t][3] - m_new);
        csum += e0 + e1 + e2 + e3;
        ushort4 ph;
        ph.x = f2bf(e0); ph.y = f2bf(e1); ph.z = f2bf(e2); ph.w = f2bf(e3);
        *(ushort4*)&Ph[w][(16 + lq) * 64 + ((16 * t + 4 * lg) ^ swz)] = ph;
      }
      csum += __shfl_xor(csum, 16);
      csum += __shfl_xor(csum, 32);
      l_reg1 = l_reg1 * fx + csum;
      m_reg1 = m_new;
      float fxr[4];
#pragma unroll
      for (int r = 0; r < 4; ++r) fxr[r] = __shfl(fx, 4 * lg + r);
#pragma unroll
      for (int t = 0; t < 4; ++t) {
        accO1[t][0] *= fxr[0]; accO1[t][1] *= fxr[1];
        accO1[t][2] *= fxr[2]; accO1[t][3] *= fxr[3];
      }
    }

    bf16x8 pa0[2], pa1[2];
#pragma unroll
    for (int ks = 0; ks < 2; ++ks) {
      int c = (8 * lg + 32 * ks) ^ swz;
      pa0[ks] = *(const bf16x8*)&Ph[w][lq * 64 + c];
      pa1[ks] = *(const bf16x8*)&Ph[w][(16 + lq) * 64 + c];
    }

    __builtin_amdgcn_s_setprio(1);
#pragma unroll
    for (int t = 0; t < 4; ++t) {
      const int vr = (16 * t + lq) * 64;
#pragma unroll
      for (int ks = 0; ks < 2; ++ks) {
        const int c = (8 * lg + 32 * ks) ^ swz;
        bf16x8 vh = *(const bf16x8*)&Vsh[bf][vr + c];
        bf16x8 vl = *(const bf16x8*)&Vsl[bf][vr + c];
        accO0[t] = MFMA16(pa0[ks], vh, accO0[t]);
        accO0[t] = MFMA16(pa0[ks], vl, accO0[t]);
        accO1[t] = MFMA16(pa1[ks], vh, accO1[t]);
        accO1[t] = MFMA16(pa1[ks], vl, accO1[t]);
      }
    }
    __builtin_amdgcn_s_setprio(0);

    if (ch < 9) {
      cM0 = nM0; cM1 = nM1;
#pragma unroll
      for (int t = 0; t < 4; ++t) { cB0[t] = nB0[t]; cB1[t] = nB1[t]; }
    }
  }
#undef STAGE

  float il0 = 1.f / l_reg0;
  float il1 = 1.f / l_reg1;
  float ilr0[4], ilr1[4];
#pragma unroll
  for (int r = 0; r < 4; ++r) {
    ilr0[r] = __shfl(il0, 4 * lg + r);
    ilr1[r] = __shfl(il1, 4 * lg + r);
  }
#pragma unroll
  for (int t = 0; t < 4; ++t)
#pragma unroll
    for (int r = 0; r < 4; ++r) {
      int g0 = q0 + 32 * w + 4 * lg + r;
      if (g0 < NN) {
        float v = accO0[t][r] * ilr0[r];
        u16 hi, lo;
        split2(v, hi, lo);
        size_t a = ((size_t)b * NN + g0) * NC + h * 64 + 16 * t + lq;
        Oh[a] = hi;
        Ol[a] = lo;
      }
      int g1 = g0 + 16;
      if (g1 < NN) {
        float v = accO1[t][r] * ilr1[r];
        u16 hi, lo;
        split2(v, hi, lo);
        size_t a = ((size_t)b * NN + g1) * NC + h * 64 + 16 * t + lq;
        Oh[a] = hi;
        Ol[a] = lo;
      }
    }
}

// ---------------------------------------------------------------------------
// Projection GEMM v5s: R11's structure + A-tile XOR swizzle. fp32 output.
// ---------------------------------------------------------------------------
__global__ __launch_bounds__(256, 3) void proj_mfma_k(
    const u16* __restrict__ Ah, const u16* __restrict__ Al,
    const u16* __restrict__ Wh, const u16* __restrict__ Wl,
    const float* __restrict__ bias, float* __restrict__ out)
{
  __shared__ u16 Ash[2][4096], Asl[2][4096];

  const int tid = threadIdx.x;
  const int w = tid >> 6, l = tid & 63, lq = l & 15, lg = l >> 4;
  const int wm = (w >> 1) * 64, wn = (w & 1) * 64;
  const int mb = blockIdx.x * 128;
  const int rb = blockIdx.y * 128;
  const int r0 = rb + wn;
  const int soff = (l >> 2) * 384 + (((l & 3) ^ ((l >> 2) & 3)) << 3);
  const int csw = (lg ^ (lq & 3)) << 3;

#define STAGE_A(k0_, bf_)                                                    \
  {                                                                          \
    _Pragma("unroll")                                                        \
    for (int j = 0; j < 2; ++j) {                                            \
      const int tr = 32 * w + 16 * j;                                        \
      const size_t ga = (size_t)(mb + tr) * 384 + (k0_) + soff;              \
      gload16(&Ah[ga], &Ash[bf_][tr * 32]);                                  \
      gload16(&Al[ga], &Asl[bf_][tr * 32]);                                  \
    }                                                                        \
  }

  const size_t brow = (size_t)(r0 + lq) * 384 + 8 * lg;
#define BLOAD(k0_, BH_, BL_)                                                 \
  {                                                                          \
    _Pragma("unroll")                                                        \
    for (int nt = 0; nt < 4; ++nt) {                                         \
      BH_[nt] = *(const bf16x8*)&Wh[brow + (size_t)(16 * nt) * 384 + (k0_)]; \
      BL_[nt] = *(const bf16x8*)&Wl[brow + (size_t)(16 * nt) * 384 + (k0_)]; \
    }                                                                        \
  }

#define COMPUTE(bf_)                                                         \
  {                                                                          \
    _Pragma("unroll")                                                        \
    for (int mt = 0; mt < 4; ++mt) {                                         \
      bf16x8 ah = *(const bf16x8*)&Ash[bf_][(wm + 16 * mt + lq) * 32 + csw]; \
      bf16x8 al = *(const bf16x8*)&Asl[bf_][(wm + 16 * mt + lq) * 32 + csw]; \
      _Pragma("unroll")                                                      \
      for (int nt = 0; nt < 4; ++nt) {                                       \
        acc[mt][nt] = MFMA16(ah, bhf[nt], acc[mt][nt]);                      \
        acc[mt][nt] = MFMA16(ah, blf[nt], acc[mt][nt]);                      \
        acc[mt][nt] = MFMA16(al, bhf[nt], acc[mt][nt]);                      \
      }                                                                      \
    }                                                                        \
  }

  bf16x8 bhf[4], blf[4], nbh[4], nbl[4];
  BLOAD(0, bhf, blf);
  STAGE_A(0, 0);
  STAGE_A(32, 1);

  f32x4 acc[4][4];
#pragma unroll
  for (int nt = 0; nt < 4; ++nt) {
    float bv = bias[r0 + 16 * nt + lq];
#pragma unroll
    for (int mt = 0; mt < 4; ++mt) acc[mt][nt] = (f32x4){bv, bv, bv, bv};
  }

  for (int k = 0; k < 11; ++k) {
    asm volatile("s_waitcnt vmcnt(4)" ::: "memory");
    SB0();
    __builtin_amdgcn_s_barrier();
    SB0();
    const int bfb = k & 1;
    COMPUTE(bfb);
    SB0();
    __builtin_amdgcn_s_barrier();
    SB0();
    BLOAD(32 * (k + 1), nbh, nbl);
    if (k < 10) STAGE_A(32 * (k + 2), bfb);
#pragma unroll
    for (int nt = 0; nt < 4; ++nt) { bhf[nt] = nbh[nt]; blf[nt] = nbl[nt]; }
  }
  asm volatile("s_waitcnt vmcnt(0)" ::: "memory");
  SB0();
  __builtin_amdgcn_s_barrier();
  SB0();
  COMPUTE(1);

#undef COMPUTE
#undef BLOAD
#undef STAGE_A

#pragma unroll
  for (int mt = 0; mt < 4; ++mt)
#pragma unroll
    for (int r = 0; r < 4; ++r) {
      int m = mb + wm + 16 * mt + 4 * lg + r;
      if (m >= MTOT) continue;
#pragma unroll
      for (int nt = 0; nt < 4; ++nt)
        out[(size_t)m * NC + r0 + 16 * nt + lq] = acc[mt][nt][r];
    }
}

// ---------------------------------------------------------------------------
extern "C" void kernel_launch(void* const* d_in, const int* in_sizes, int n_in,
                              void* d_out, int out_size, void* d_ws, size_t ws_size,
                              hipStream_t stream) {
  const float* x       = (const float*)d_in[0];
  const float* qkv_w   = (const float*)d_in[1];
  const float* qkv_b   = (const float*)d_in[2];
  const float* proj_w  = (const float*)d_in[3];
  const float* proj_b  = (const float*)d_in[4];
  const float* rel_pos = (const float*)d_in[5];
  const int*   rel_idx = (const int*)d_in[6];
  const int*   mask    = (const int*)d_in[7];
  const int*   patch   = (const int*)d_in[8];
  float* out = (float*)d_out;
  u16* W16 = (u16*)d_ws;

  unsigned* pmp = (unsigned*)(W16 + OFF_PM);
  u16* btblp = W16 + OFF_BT;

  prep_k<<<9850, 256, 0, stream>>>(x, qkv_w, proj_w, mask, rel_pos, rel_idx,
                                   patch, W16);
  qkv_mfma_k<<<657, 256, 0, stream>>>(
      W16 + OFF_XH, W16 + OFF_XL, W16 + OFF_WQH, W16 + OFF_WQL, qkv_b, W16);
  attn_k<<<dim3(5, NH, NB), 256, 0, stream>>>(
      W16 + OFF_QH, W16 + OFF_QL, W16 + OFF_KH, W16 + OFF_KL,
      W16 + OFF_VTH, W16 + OFF_VTL, btblp, pmp,
      W16 + OFF_XH, W16 + OFF_XL);
  proj_mfma_k<<<dim3(73, 3), 256, 0, stream>>>(
      W16 + OFF_XH, W16 + OFF_XL, W16 + OFF_WPH, W16 + OFF_WPL, proj_b, out);
}